// Round 1
// baseline (17584.785 us; speedup 1.0000x reference)
//
#include <hip/hip_runtime.h>
#include <math.h>

// TemporalDecoder: 2-layer LSTM (B=256, H=512), 128 encode steps + 32 decode steps.
// Round 1: correctness-first fp32. One cell kernel per (step, layer), fc kernel per
// decode step. Grid sized to exactly cover 256 CUs (16x16 = 256 WGs).

#define BB 256   // batch
#define SS 128   // encode sequence length
#define HH 512   // hidden
#define NSTEPS 32

#define KB 32    // K-tile

// Cell kernel: computes h_new = LSTMCell(A, h_prev) for one layer.
// Tile: BM=16 batch rows x BN=32 h-cols -> 128 gate cols (4 gates x 32).
// Thread (ty 0..7, tx 0..31): acc[2 rows][4 gates] so the full i,f,g,o for an
// (row, col) pair lives in one thread -> elementwise cell done in-register.
__global__ __launch_bounds__(256) void lstm_cell(
    const float* __restrict__ A, int lda,          // input activations [B x 512], row stride lda
    const float* __restrict__ Hp,                  // h_prev [B x 512]
    const float* __restrict__ Wi,                  // W_ih layer slice [2048 x 512]
    const float* __restrict__ Wh,                  // W_hh layer slice [2048 x 512]
    const float* __restrict__ bi,                  // b_ih layer slice [2048]
    const float* __restrict__ bh,                  // b_hh layer slice [2048]
    float* __restrict__ Hn,                        // h_new [B x 512]
    float* __restrict__ C)                         // c state in/out [B x 512]
{
    __shared__ float sA[16][KB + 1];
    __shared__ float sW[128][KB + 1];

    const int tid = threadIdx.x;
    const int tx = tid & 31;        // h-col within tile
    const int ty = tid >> 5;        // row pair index
    const int bm0 = blockIdx.x * 16;
    const int bn0 = blockIdx.y * 32;

    float acc[2][4];
    #pragma unroll
    for (int r = 0; r < 2; ++r)
        #pragma unroll
        for (int q = 0; q < 4; ++q) {
            int gcol = q * HH + bn0 + tx;   // gate order: i, f, g, o
            acc[r][q] = bi[gcol] + bh[gcol];
        }

    // Phase 0: A @ Wi^T ; Phase 1: Hp @ Wh^T  (fused K=1024 total)
    #pragma unroll 1
    for (int phase = 0; phase < 2; ++phase) {
        const float* Ap = phase ? Hp : A;
        const int ldap  = phase ? HH : lda;
        const float* Wp = phase ? Wh : Wi;
        #pragma unroll 1
        for (int k0 = 0; k0 < HH; k0 += KB) {
            __syncthreads();
            // stage A tile: 16x32, 2 elems/thread, coalesced in k
            {
                int i = tid >> 5;
                int k = tid & 31;
                sA[i][k]     = Ap[(size_t)(bm0 + i) * ldap + k0 + k];
                sA[i + 8][k] = Ap[(size_t)(bm0 + i + 8) * ldap + k0 + k];
            }
            // stage W tile: 128x32, 16 elems/thread, coalesced in k
            {
                int k  = tid & 31;
                int w0 = tid >> 5;
                #pragma unroll
                for (int c = 0; c < 16; ++c) {
                    int w = w0 + c * 8;          // 0..127 local gate-col
                    int q = w >> 5;
                    int j = w & 31;
                    sW[w][k] = Wp[(size_t)(q * HH + bn0 + j) * HH + k0 + k];
                }
            }
            __syncthreads();
            #pragma unroll
            for (int k = 0; k < KB; ++k) {
                float a0 = sA[ty * 2 + 0][k];
                float a1 = sA[ty * 2 + 1][k];
                #pragma unroll
                for (int q = 0; q < 4; ++q) {
                    float w = sW[q * 32 + tx][k];
                    acc[0][q] += a0 * w;
                    acc[1][q] += a1 * w;
                }
            }
        }
    }

    // elementwise cell (i,f,g,o order per PyTorch/JAX reference)
    #pragma unroll
    for (int r = 0; r < 2; ++r) {
        int row = bm0 + ty * 2 + r;
        int col = bn0 + tx;
        size_t idx = (size_t)row * HH + col;
        float ig = 1.f / (1.f + __expf(-acc[r][0]));
        float fg = 1.f / (1.f + __expf(-acc[r][1]));
        float gg = tanhf(acc[r][2]);
        float og = 1.f / (1.f + __expf(-acc[r][3]));
        float c_new = fg * C[idx] + ig * gg;
        C[idx] = c_new;
        Hn[idx] = og * tanhf(c_new);
    }
}

// fc kernel: pred = Hin @ Wout^T + bout. Writes pred buffer AND out[:, step, 0, :].
// Tile 16 rows x 128 cols; grid (B/16) x (512/128) = 16x4.
__global__ __launch_bounds__(256) void fc_kernel(
    const float* __restrict__ Hin,
    const float* __restrict__ Wout,   // [512 x 512]
    const float* __restrict__ bout,   // [512]
    float* __restrict__ pred,         // [B x 512]
    float* __restrict__ out,          // [B x NSTEPS x 1 x 512]
    int step)
{
    __shared__ float sA[16][KB + 1];
    __shared__ float sW[128][KB + 1];

    const int tid = threadIdx.x;
    const int tx = tid & 31;
    const int ty = tid >> 5;
    const int bm0 = blockIdx.x * 16;
    const int bn0 = blockIdx.y * 128;

    float acc[2][4];
    #pragma unroll
    for (int r = 0; r < 2; ++r)
        #pragma unroll
        for (int q = 0; q < 4; ++q)
            acc[r][q] = bout[bn0 + q * 32 + tx];

    #pragma unroll 1
    for (int k0 = 0; k0 < HH; k0 += KB) {
        __syncthreads();
        {
            int i = tid >> 5;
            int k = tid & 31;
            sA[i][k]     = Hin[(size_t)(bm0 + i) * HH + k0 + k];
            sA[i + 8][k] = Hin[(size_t)(bm0 + i + 8) * HH + k0 + k];
        }
        {
            int k  = tid & 31;
            int w0 = tid >> 5;
            #pragma unroll
            for (int c = 0; c < 16; ++c) {
                int w = w0 + c * 8;
                sW[w][k] = Wout[(size_t)(bn0 + w) * HH + k0 + k];
            }
        }
        __syncthreads();
        #pragma unroll
        for (int k = 0; k < KB; ++k) {
            float a0 = sA[ty * 2 + 0][k];
            float a1 = sA[ty * 2 + 1][k];
            #pragma unroll
            for (int q = 0; q < 4; ++q) {
                float w = sW[q * 32 + tx][k];
                acc[0][q] += a0 * w;
                acc[1][q] += a1 * w;
            }
        }
    }

    #pragma unroll
    for (int r = 0; r < 2; ++r) {
        int row = bm0 + ty * 2 + r;
        #pragma unroll
        for (int q = 0; q < 4; ++q) {
            int col = bn0 + q * 32 + tx;
            float v = acc[r][q];
            pred[(size_t)row * HH + col] = v;
            out[((size_t)row * NSTEPS + step) * HH + col] = v;
        }
    }
}

extern "C" void kernel_launch(void* const* d_in, const int* in_sizes, int n_in,
                              void* d_out, int out_size, void* d_ws, size_t ws_size,
                              hipStream_t stream)
{
    const float* x     = (const float*)d_in[0];   // [B, S, H]
    const float* W_ih  = (const float*)d_in[1];   // [L, 4H, H]
    const float* W_hh  = (const float*)d_in[2];   // [L, 4H, H]
    const float* b_ih  = (const float*)d_in[3];   // [L, 4H]
    const float* b_hh  = (const float*)d_in[4];   // [L, 4H]
    const float* W_out = (const float*)d_in[5];   // [F, H]
    const float* b_out = (const float*)d_in[6];   // [F]
    float* out = (float*)d_out;
    (void)in_sizes; (void)n_in; (void)out_size; (void)ws_size;

    const size_t SB = (size_t)BB * HH;            // 131072 floats per state buffer
    float* ws = (float*)d_ws;
    float* h0[2] = { ws + 0 * SB, ws + 1 * SB };
    float* h1[2] = { ws + 2 * SB, ws + 3 * SB };
    float* c0    = ws + 4 * SB;
    float* c1    = ws + 5 * SB;
    float* pred  = ws + 6 * SB;

    // zero initial states (h0,h1,c0,c1) + pred each call (deterministic)
    hipMemsetAsync(d_ws, 0, 7 * SB * sizeof(float), stream);

    const size_t WOFF = (size_t)4 * HH * HH;      // per-layer weight slice
    const size_t BOFF = (size_t)4 * HH;

    dim3 cgrid(BB / 16, HH / 32);                 // 16 x 16 = 256 WGs
    dim3 fgrid(BB / 16, HH / 128);                // 16 x 4
    dim3 blk(256);

    int cur = 0;
    // ---- encode: 128 steps ----
    for (int t = 0; t < SS; ++t) {
        int nxt = cur ^ 1;
        lstm_cell<<<cgrid, blk, 0, stream>>>(x + (size_t)t * HH, SS * HH, h0[cur],
                                             W_ih, W_hh, b_ih, b_hh, h0[nxt], c0);
        lstm_cell<<<cgrid, blk, 0, stream>>>(h0[nxt], HH, h1[cur],
                                             W_ih + WOFF, W_hh + WOFF,
                                             b_ih + BOFF, b_hh + BOFF, h1[nxt], c1);
        cur = nxt;
    }
    // ---- decode: 32 steps ----
    for (int s = 0; s < NSTEPS; ++s) {
        int nxt = cur ^ 1;
        fc_kernel<<<fgrid, blk, 0, stream>>>(h1[cur], W_out, b_out, pred, out, s);
        lstm_cell<<<cgrid, blk, 0, stream>>>(pred, HH, h0[cur],
                                             W_ih, W_hh, b_ih, b_hh, h0[nxt], c0);
        lstm_cell<<<cgrid, blk, 0, stream>>>(h0[nxt], HH, h1[cur],
                                             W_ih + WOFF, W_hh + WOFF,
                                             b_ih + BOFF, b_hh + BOFF, h1[nxt], c1);
        cur = nxt;
    }
}

// Round 2
// 7996.690 us; speedup vs baseline: 2.1990x; 2.1990x over previous
//
#include <hip/hip_runtime.h>
#include <math.h>

// TemporalDecoder round 2: bf16x3 (hi/lo split) MFMA cells + MFMA fc.
// G = A@Wi^T + Hp@Wh^T via mfma_f32_16x16x32_bf16, fp32 accumulate.
// a*w ~= ah*wh + ah*wl + al*wh  (lo*lo dropped): fp32-like accuracy.

#define BB 256
#define SS 128
#define HH 512
#define NSTEPS 32

typedef __attribute__((ext_vector_type(8))) short s16x8;
typedef __attribute__((ext_vector_type(4))) float f32x4;

__device__ __forceinline__ ushort rne_bf16(float f) {
    union { float f; unsigned u; } x; x.f = f;
    unsigned r = x.u + 0x7FFFu + ((x.u >> 16) & 1u);
    return (ushort)(r >> 16);
}
__device__ __forceinline__ float bf16_to_f(ushort h) {
    union { unsigned u; float f; } x; x.u = ((unsigned)h) << 16;
    return x.f;
}

// Split fp32 weights into bf16 hi/lo arrays. 4 elems/thread.
__global__ __launch_bounds__(256) void split_w(const float* __restrict__ src,
                                               ushort* __restrict__ hi,
                                               ushort* __restrict__ lo, int n4) {
    int i = blockIdx.x * blockDim.x + threadIdx.x;
    if (i >= n4) return;
    float4 f = ((const float4*)src)[i];
    float ff[4] = {f.x, f.y, f.z, f.w};
    ushort h[4], l[4];
    #pragma unroll
    for (int j = 0; j < 4; ++j) {
        h[j] = rne_bf16(ff[j]);
        l[j] = rne_bf16(ff[j] - bf16_to_f(h[j]));
    }
    ((ushort4*)hi)[i] = make_ushort4(h[0], h[1], h[2], h[3]);
    ((ushort4*)lo)[i] = make_ushort4(l[0], l[1], l[2], l[3]);
}

// LSTM cell, bf16x3 MFMA. Grid: 256 1-D WGs -> (m-block 0..3 [64 rows], hc-block
// 0..63 [8 h-cols x 4 gates]), XCD-grouped. WG = 256 thr = 4 waves (2m x 2n).
// n-local (0..31) = hc*4 + g so all 4 gates of an (row,hcol) sit in one 16-wide
// fragment -> 4-lane shfl gather for the elementwise cell.
__global__ __launch_bounds__(256) void lstm_cell_mfma(
    const float* __restrict__ Af32,                 // fp32 A (encode layer0) or null
    const ushort* __restrict__ Ahi, const ushort* __restrict__ Alo,  // bf16 A else
    int lda,
    const ushort* __restrict__ Hphi, const ushort* __restrict__ Hplo,
    const ushort* __restrict__ Wihi, const ushort* __restrict__ Wilo,
    const ushort* __restrict__ Whhi, const ushort* __restrict__ Whlo,
    const float* __restrict__ bi, const float* __restrict__ bh,
    ushort* __restrict__ Hnhi, ushort* __restrict__ Hnlo,
    float* __restrict__ C)
{
    __shared__ __align__(16) ushort sA[2][2][64][64];   // [buf][hi/lo][row][k] 32KB
    __shared__ __align__(16) ushort sW[2][2][32][64];   // 16KB

    const int tid = threadIdx.x;
    const int lane = tid & 63;
    const int wid = tid >> 6;
    const int wm = wid >> 1, wn = wid & 1;

    // XCD-grouped decode: XCD k owns hc-blocks 8k..8k+7 (x4 m) -> ~2MB weights/XCD in L2
    const int lin = blockIdx.x;
    const int xcd = lin & 7, grp = lin >> 3;
    const int bm0 = (grp & 3) * 64;
    const int hcb = xcd * 8 + (grp >> 2);

    const int lr = lane & 15;
    const int nloc = wn * 16 + lr;
    const int g = nloc & 3, hc = nloc >> 2;
    const int hcol = hcb * 8 + hc;
    const int gc = g * HH + hcol;

    f32x4 acc[2];
    {
        float bv = bi[gc] + bh[gc];
        acc[0] = (f32x4){bv, bv, bv, bv};
        acc[1] = acc[0];
    }

    auto stage = [&](int buf, int it) {
        const int ph = it >> 3;            // 0: input GEMM, 1: recurrent GEMM
        const int k0 = (it & 7) * 64;
        {   // W tile 32x64 hi+lo
            const int r = tid >> 3, ck = tid & 7;
            const int wrow = (r & 3) * HH + hcb * 8 + (r >> 2);
            const ushort* whi = ph ? Whhi : Wihi;
            const ushort* wlo = ph ? Whlo : Wilo;
            const int sw = ((ck ^ (r & 7)) << 3);
            *(uint4*)&sW[buf][0][r][sw] = *(const uint4*)&whi[(size_t)wrow * HH + k0 + ck * 8];
            *(uint4*)&sW[buf][1][r][sw] = *(const uint4*)&wlo[(size_t)wrow * HH + k0 + ck * 8];
        }
        {   // A tile 64x64 hi+lo
            const int r = tid >> 2, cb = (tid & 3) * 2;
            if (ph == 0 && Af32) {
                #pragma unroll
                for (int j = 0; j < 2; ++j) {
                    int ck = cb + j;
                    const float* src = &Af32[(size_t)(bm0 + r) * lda + k0 + ck * 8];
                    float4 f0 = *(const float4*)src;
                    float4 f1 = *(const float4*)(src + 4);
                    float ff[8] = {f0.x, f0.y, f0.z, f0.w, f1.x, f1.y, f1.z, f1.w};
                    union { ushort u[8]; uint4 v; } Hx, Lx;
                    #pragma unroll
                    for (int e = 0; e < 8; ++e) {
                        ushort hb = rne_bf16(ff[e]);
                        Hx.u[e] = hb;
                        Lx.u[e] = rne_bf16(ff[e] - bf16_to_f(hb));
                    }
                    const int sw = ((ck ^ (r & 7)) << 3);
                    *(uint4*)&sA[buf][0][r][sw] = Hx.v;
                    *(uint4*)&sA[buf][1][r][sw] = Lx.v;
                }
            } else {
                const ushort* ahi = (ph == 0) ? Ahi : Hphi;
                const ushort* alo = (ph == 0) ? Alo : Hplo;
                const int ld = (ph == 0) ? lda : HH;
                #pragma unroll
                for (int j = 0; j < 2; ++j) {
                    int ck = cb + j;
                    const int sw = ((ck ^ (r & 7)) << 3);
                    *(uint4*)&sA[buf][0][r][sw] = *(const uint4*)&ahi[(size_t)(bm0 + r) * ld + k0 + ck * 8];
                    *(uint4*)&sA[buf][1][r][sw] = *(const uint4*)&alo[(size_t)(bm0 + r) * ld + k0 + ck * 8];
                }
            }
        }
    };

    auto compute = [&](int buf) {
        #pragma unroll
        for (int ks = 0; ks < 2; ++ks) {
            const int ckb = ks * 4 + (lane >> 4);
            const int rb = nloc;
            const int swb = ((ckb ^ (rb & 7)) << 3);
            s16x8 b0 = *(const s16x8*)&sW[buf][0][rb][swb];
            s16x8 b1 = *(const s16x8*)&sW[buf][1][rb][swb];
            const int r0 = wm * 32 + lr;
            const int sw0 = ((ckb ^ (r0 & 7)) << 3);
            s16x8 a00 = *(const s16x8*)&sA[buf][0][r0][sw0];
            s16x8 a01 = *(const s16x8*)&sA[buf][1][r0][sw0];
            const int r1 = r0 + 16;
            const int sw1 = ((ckb ^ (r1 & 7)) << 3);
            s16x8 a10 = *(const s16x8*)&sA[buf][0][r1][sw1];
            s16x8 a11 = *(const s16x8*)&sA[buf][1][r1][sw1];
            acc[0] = __builtin_amdgcn_mfma_f32_16x16x32_bf16(a00, b0, acc[0], 0, 0, 0);
            acc[0] = __builtin_amdgcn_mfma_f32_16x16x32_bf16(a00, b1, acc[0], 0, 0, 0);
            acc[0] = __builtin_amdgcn_mfma_f32_16x16x32_bf16(a01, b0, acc[0], 0, 0, 0);
            acc[1] = __builtin_amdgcn_mfma_f32_16x16x32_bf16(a10, b0, acc[1], 0, 0, 0);
            acc[1] = __builtin_amdgcn_mfma_f32_16x16x32_bf16(a10, b1, acc[1], 0, 0, 0);
            acc[1] = __builtin_amdgcn_mfma_f32_16x16x32_bf16(a11, b0, acc[1], 0, 0, 0);
        }
    };

    int buf = 0;
    stage(0, 0);
    __syncthreads();
    #pragma unroll 1
    for (int it = 0; it < 16; ++it) {
        if (it < 15) stage(buf ^ 1, it + 1);
        compute(buf);
        __syncthreads();
        buf ^= 1;
    }

    // epilogue: gather 4 gates across the 4-lane group, apply cell, store
    #pragma unroll
    for (int fm = 0; fm < 2; ++fm) {
        #pragma unroll
        for (int j = 0; j < 4; ++j) {
            float v = acc[fm][j];
            float s1 = __shfl_xor(v, 1, 64);
            float s2 = __shfl_xor(v, 2, 64);
            float s3 = __shfl_xor(v, 3, 64);
            auto selk = [&](int k) { return (k == 0) ? v : (k == 1) ? s1 : (k == 2) ? s2 : s3; };
            float pi = selk(g), pf = selk(g ^ 1), pg = selk(g ^ 2), po = selk(g ^ 3);
            int row = bm0 + wm * 32 + fm * 16 + (lane >> 4) * 4 + j;
            size_t idx = (size_t)row * HH + hcol;
            float ig = 1.f / (1.f + __expf(-pi));
            float fg = 1.f / (1.f + __expf(-pf));
            float e2g = __expf(2.f * fminf(fmaxf(pg, -20.f), 20.f));
            float gg = (e2g - 1.f) / (e2g + 1.f);
            float og = 1.f / (1.f + __expf(-po));
            float cn = fg * C[idx] + ig * gg;
            float e2c = __expf(2.f * fminf(fmaxf(cn, -20.f), 20.f));
            float th = (e2c - 1.f) / (e2c + 1.f);
            float hn = og * th;
            if (g == 0) {
                C[idx] = cn;
                ushort hb = rne_bf16(hn);
                Hnhi[idx] = hb;
                Hnlo[idx] = rne_bf16(hn - bf16_to_f(hb));
            }
        }
    }
}

// fc: pred = h1 @ Wout^T + bout, bf16x3 MFMA. Writes pred hi/lo + out fp32.
// Grid (8,16): 32x32 tiles, 4 waves (2m x 2n), wave tile 16x16.
__global__ __launch_bounds__(256) void fc_mfma(
    const ushort* __restrict__ Ahi, const ushort* __restrict__ Alo,
    const ushort* __restrict__ Whi, const ushort* __restrict__ Wlo,
    const float* __restrict__ bout,
    ushort* __restrict__ Phi, ushort* __restrict__ Plo,
    float* __restrict__ out, int step)
{
    __shared__ __align__(16) ushort sA[2][2][32][64];
    __shared__ __align__(16) ushort sW[2][2][32][64];
    const int tid = threadIdx.x;
    const int lane = tid & 63, wid = tid >> 6;
    const int wm = wid >> 1, wn = wid & 1;
    const int bm0 = blockIdx.x * 32, bn0 = blockIdx.y * 32;
    const int lr = lane & 15;
    const int col = bn0 + wn * 16 + lr;

    f32x4 acc;
    { float bv = bout[col]; acc = (f32x4){bv, bv, bv, bv}; }

    auto stage = [&](int buf, int it) {
        const int k0 = it * 64;
        const int r = tid >> 3, ck = tid & 7;
        const int sw = ((ck ^ (r & 7)) << 3);
        *(uint4*)&sW[buf][0][r][sw] = *(const uint4*)&Whi[(size_t)(bn0 + r) * HH + k0 + ck * 8];
        *(uint4*)&sW[buf][1][r][sw] = *(const uint4*)&Wlo[(size_t)(bn0 + r) * HH + k0 + ck * 8];
        *(uint4*)&sA[buf][0][r][sw] = *(const uint4*)&Ahi[(size_t)(bm0 + r) * HH + k0 + ck * 8];
        *(uint4*)&sA[buf][1][r][sw] = *(const uint4*)&Alo[(size_t)(bm0 + r) * HH + k0 + ck * 8];
    };
    auto compute = [&](int buf) {
        #pragma unroll
        for (int ks = 0; ks < 2; ++ks) {
            const int ckb = ks * 4 + (lane >> 4);
            const int rb = wn * 16 + lr;
            const int swb = ((ckb ^ (rb & 7)) << 3);
            s16x8 b0 = *(const s16x8*)&sW[buf][0][rb][swb];
            s16x8 b1 = *(const s16x8*)&sW[buf][1][rb][swb];
            const int ra = wm * 16 + lr;
            const int swa = ((ckb ^ (ra & 7)) << 3);
            s16x8 a0 = *(const s16x8*)&sA[buf][0][ra][swa];
            s16x8 a1 = *(const s16x8*)&sA[buf][1][ra][swa];
            acc = __builtin_amdgcn_mfma_f32_16x16x32_bf16(a0, b0, acc, 0, 0, 0);
            acc = __builtin_amdgcn_mfma_f32_16x16x32_bf16(a0, b1, acc, 0, 0, 0);
            acc = __builtin_amdgcn_mfma_f32_16x16x32_bf16(a1, b0, acc, 0, 0, 0);
        }
    };

    int buf = 0;
    stage(0, 0);
    __syncthreads();
    #pragma unroll 1
    for (int it = 0; it < 8; ++it) {
        if (it < 7) stage(buf ^ 1, it + 1);
        compute(buf);
        __syncthreads();
        buf ^= 1;
    }

    #pragma unroll
    for (int j = 0; j < 4; ++j) {
        int row = bm0 + wm * 16 + (lane >> 4) * 4 + j;
        float v = acc[j];
        size_t pidx = (size_t)row * HH + col;
        ushort hb = rne_bf16(v);
        Phi[pidx] = hb;
        Plo[pidx] = rne_bf16(v - bf16_to_f(hb));
        out[((size_t)row * NSTEPS + step) * HH + col] = v;
    }
}

extern "C" void kernel_launch(void* const* d_in, const int* in_sizes, int n_in,
                              void* d_out, int out_size, void* d_ws, size_t ws_size,
                              hipStream_t stream)
{
    const float* x     = (const float*)d_in[0];   // [B, S, H]
    const float* W_ih  = (const float*)d_in[1];   // [L, 4H, H]
    const float* W_hh  = (const float*)d_in[2];   // [L, 4H, H]
    const float* b_ih  = (const float*)d_in[3];   // [L, 4H]
    const float* b_hh  = (const float*)d_in[4];   // [L, 4H]
    const float* W_out = (const float*)d_in[5];   // [F, H]
    const float* b_out = (const float*)d_in[6];   // [F]
    float* out = (float*)d_out;
    (void)in_sizes; (void)n_in; (void)out_size; (void)ws_size;

    const size_t SB = (size_t)BB * HH;            // 131072 elems per state
    ushort* p = (ushort*)d_ws;
    ushort* h0hi[2] = {p, p + SB}; p += 2 * SB;
    ushort* h0lo[2] = {p, p + SB}; p += 2 * SB;
    ushort* h1hi[2] = {p, p + SB}; p += 2 * SB;
    ushort* h1lo[2] = {p, p + SB}; p += 2 * SB;
    ushort* predhi = p; p += SB;
    ushort* predlo = p; p += SB;
    float* c0 = (float*)p;
    float* c1 = c0 + SB;
    char* zend = (char*)(c1 + SB);
    size_t zbytes = zend - (char*)d_ws;           // ~3.7 MB zero-init region

    ushort* q = (ushort*)zend;
    const size_t WL = (size_t)4 * HH * HH;        // per-layer W slice elems (1,048,576)
    ushort* wihhi = q; q += 2 * WL;
    ushort* wihlo = q; q += 2 * WL;
    ushort* whhhi = q; q += 2 * WL;
    ushort* whhlo = q; q += 2 * WL;
    ushort* wouthi = q; q += (size_t)HH * HH;
    ushort* woutlo = q; q += (size_t)HH * HH;

    hipMemsetAsync(d_ws, 0, zbytes, stream);

    dim3 blk(256);
    {
        int n4 = (int)((2 * WL) / 4);
        split_w<<<dim3((n4 + 255) / 256), blk, 0, stream>>>(W_ih, wihhi, wihlo, n4);
        split_w<<<dim3((n4 + 255) / 256), blk, 0, stream>>>(W_hh, whhhi, whhlo, n4);
        int m4 = (int)(((size_t)HH * HH) / 4);
        split_w<<<dim3((m4 + 255) / 256), blk, 0, stream>>>(W_out, wouthi, woutlo, m4);
    }

    const size_t BOFF = (size_t)4 * HH;
    int cur = 0;
    // ---- encode: 128 steps ----
    for (int t = 0; t < SS; ++t) {
        int nxt = cur ^ 1;
        lstm_cell_mfma<<<256, blk, 0, stream>>>(x + (size_t)t * HH, nullptr, nullptr, SS * HH,
            h0hi[cur], h0lo[cur], wihhi, wihlo, whhhi, whhlo, b_ih, b_hh,
            h0hi[nxt], h0lo[nxt], c0);
        lstm_cell_mfma<<<256, blk, 0, stream>>>(nullptr, h0hi[nxt], h0lo[nxt], HH,
            h1hi[cur], h1lo[cur], wihhi + WL, wihlo + WL, whhhi + WL, whhlo + WL,
            b_ih + BOFF, b_hh + BOFF, h1hi[nxt], h1lo[nxt], c1);
        cur = nxt;
    }
    // ---- decode: 32 steps ----
    for (int s = 0; s < NSTEPS; ++s) {
        int nxt = cur ^ 1;
        fc_mfma<<<dim3(8, 16), blk, 0, stream>>>(h1hi[cur], h1lo[cur], wouthi, woutlo,
            b_out, predhi, predlo, out, s);
        lstm_cell_mfma<<<256, blk, 0, stream>>>(nullptr, predhi, predlo, HH,
            h0hi[cur], h0lo[cur], wihhi, wihlo, whhhi, whhlo, b_ih, b_hh,
            h0hi[nxt], h0lo[nxt], c0);
        lstm_cell_mfma<<<256, blk, 0, stream>>>(nullptr, h0hi[nxt], h0lo[nxt], HH,
            h1hi[cur], h1lo[cur], wihhi + WL, wihlo + WL, whhhi + WL, whhlo + WL,
            b_ih + BOFF, b_hh + BOFF, h1hi[nxt], h1lo[nxt], c1);
        cur = nxt;
    }
}